// Round 4
// baseline (1805.782 us; speedup 1.0000x reference)
//
#include <hip/hip_runtime.h>

// ============================================================================
// VQ-VAE forward, MI355X fp32. Internal layout NHWC; outputs NCHW.
// B=4096. x(4096,1,28,28) -> h1(4096,14,14,32) -> h2(4096,7,7,64)
//   -> z -> VQ(512 codes, D=64) -> d0 -> d1(4096,14,14,32) -> recon.
// VQ argmin reproduces np fp32 semantics exactly:
//   dist = fl( fl(SZ + SC_k) - 2*dot(z,c_k) ), SZ/SC via numpy pairwise-8,
//   dot via sequential-K fma (BLAS order), first-min-wins tie break.
// R2 lesson: unrolled tap loop -> 256-VGPR cap -> scratch spill -> 12 GB HBM.
// R3 lesson: barrier-delimited weight staging leaves global latency on the
//   critical path (k2 VALUBusy 43%). Fix: G=2 images/block (2x FMA per
//   barrier) + register-prefetch of next weight slice during compute.
// Workspace (floats): h1/d1 @0 (25,690,112) | h2/zq @25,690,112 (12,845,056)
//   | z/d0 @38,535,168 (12,845,056) | cn @51,380,224 (512) | loss @51,380,736
// Out (floats): recon@0, z@3,211,264, z_q@16,056,320, loss@28,901,376,
//   idx@28,901,377 (200,704)
// ============================================================================

#define NB 4096

__device__ __forceinline__ float4 f4fma(float s, float4 w, float4 a) {
  a.x = fmaf(s, w.x, a.x); a.y = fmaf(s, w.y, a.y);
  a.z = fmaf(s, w.z, a.z); a.w = fmaf(s, w.w, a.w);
  return a;
}
__device__ __forceinline__ float4 f4relu(float4 a) {
  a.x = fmaxf(a.x, 0.f); a.y = fmaxf(a.y, 0.f);
  a.z = fmaxf(a.z, 0.f); a.w = fmaxf(a.w, 0.f);
  return a;
}
__device__ __forceinline__ float4 f4addrn(float4 a, float4 b) {
  a.x = __fadd_rn(a.x, b.x); a.y = __fadd_rn(a.y, b.y);
  a.z = __fadd_rn(a.z, b.z); a.w = __fadd_rn(a.w, b.w);
  return a;
}

// numpy pairwise-8 sum of squares over 64 contiguous values
__device__ __forceinline__ float np_sumsq64(const float* v) {
  float r[8];
#pragma unroll
  for (int j = 0; j < 8; ++j) r[j] = __fmul_rn(v[j], v[j]);
#pragma unroll
  for (int i = 8; i < 64; i += 8)
#pragma unroll
    for (int j = 0; j < 8; ++j) r[j] = __fadd_rn(r[j], __fmul_rn(v[i + j], v[i + j]));
  return __fadd_rn(__fadd_rn(__fadd_rn(r[0], r[1]), __fadd_rn(r[2], r[3])),
                   __fadd_rn(__fadd_rn(r[4], r[5]), __fadd_rn(r[6], r[7])));
}

// ---- K0: codebook norms (numpy-order) + zero loss accumulator --------------
__global__ __launch_bounds__(256) void k0_init(const float* __restrict__ cb,
                                               float* __restrict__ cn,
                                               float* __restrict__ loss) {
  int t = threadIdx.x;
  if (t == 0) *loss = 0.f;
  for (int k = t; k < 512; k += 256) cn[k] = np_sumsq64(&cb[k * 64]);
}

// ---- K1: conv1 4x4 s2 p1, 1->32, bias-after, ReLU. out h1 NHWC -------------
__global__ __launch_bounds__(256) void k1_conv1(const float* __restrict__ x,
                                                const float* __restrict__ w1,
                                                const float* __restrict__ b1,
                                                float* __restrict__ h1) {
  __shared__ float xs[784];
  __shared__ float wl[512];
  __shared__ float bs[32];
  int n = blockIdx.x, t = threadIdx.x;
  for (int j = t; j < 784; j += 256) xs[j] = x[n * 784 + j];
  for (int j = t; j < 512; j += 256) wl[j] = w1[j];
  if (t < 32) bs[t] = b1[t];
  __syncthreads();
  int c = t & 31, pg = t >> 5;
  for (int s = pg; s < 196; s += 8) {
    int oh = s / 14, ow = s % 14;
    float acc = 0.f;
#pragma unroll
    for (int kh = 0; kh < 4; ++kh) {
      int ih = 2 * oh - 1 + kh;
      if (ih < 0 || ih >= 28) continue;
#pragma unroll
      for (int kw = 0; kw < 4; ++kw) {
        int iw = 2 * ow - 1 + kw;
        if (iw < 0 || iw >= 28) continue;
        acc = fmaf(xs[ih * 28 + iw], wl[(kh * 4 + kw) * 32 + c], acc);
      }
    }
    acc = __fadd_rn(acc, bs[c]);
    h1[(n * 196 + s) * 32 + c] = fmaxf(acc, 0.f);
  }
}

// ---- K2: conv2 4x4 s2 p1, 32->64, bias-after, ReLU. NHWC -------------------
// G=2 images per block; next weight slice prefetched into regs during compute.
__global__ __launch_bounds__(256) void k2_conv2(const float* __restrict__ h1,
                                                const float* __restrict__ w2,
                                                const float* __restrict__ b2,
                                                float* __restrict__ h2) {
  __shared__ float xs[2][196 * 36];  // rows padded 32->36 floats
  __shared__ float wl[2048];         // one kk slice [ci][64co]
  int nb = blockIdx.x, t = threadIdx.x;
  size_t n0 = (size_t)nb * 2;
  for (int j = t; j < 6272; j += 256) {
    int o = (j >> 5) * 36 + (j & 31);
    xs[0][o] = h1[n0 * 6272 + j];
    xs[1][o] = h1[(n0 + 1) * 6272 + j];
  }
  int cg = t & 15, pgr = t >> 4, c0 = cg * 4;
  float4 bias = *(const float4*)&b2[c0];
  float4 acc0[4], acc1[4];
  int sarr[4]; bool val[4]; int ohh[4], oww[4];
#pragma unroll
  for (int p = 0; p < 4; ++p) {
    int s = pgr + p * 16;
    sarr[p] = s; val[p] = (s < 49);
    ohh[p] = s / 7; oww[p] = s % 7;
    acc0[p] = make_float4(0.f, 0.f, 0.f, 0.f);
    acc1[p] = acc0[p];
  }
  // prefetch kk=0 weight slice (8 floats/thread)
  float4 wr0 = *(const float4*)&w2[t * 8];
  float4 wr1 = *(const float4*)&w2[t * 8 + 4];
#pragma unroll 1
  for (int kk = 0; kk < 16; ++kk) {
    int kh = kk >> 2, kw = kk & 3;
    __syncthreads();                       // all readers done with prev slice
    *(float4*)&wl[t * 8] = wr0;
    *(float4*)&wl[t * 8 + 4] = wr1;
    __syncthreads();                       // slice visible
    if (kk < 15) {                         // prefetch next; vmcnt waits next iter
      wr0 = *(const float4*)&w2[(kk + 1) * 2048 + t * 8];
      wr1 = *(const float4*)&w2[(kk + 1) * 2048 + t * 8 + 4];
    }
    int base[4]; bool v[4];
#pragma unroll
    for (int p = 0; p < 4; ++p) {
      int ih = 2 * ohh[p] - 1 + kh, iw = 2 * oww[p] - 1 + kw;
      v[p] = val[p] && ih >= 0 && ih < 14 && iw >= 0 && iw < 14;
      base[p] = (ih * 14 + iw) * 36;
    }
#pragma unroll
    for (int ci = 0; ci < 32; ci += 4) {
      float4 w0 = *(float4*)&wl[(ci + 0) * 64 + c0];
      float4 w1_ = *(float4*)&wl[(ci + 1) * 64 + c0];
      float4 w2_ = *(float4*)&wl[(ci + 2) * 64 + c0];
      float4 w3_ = *(float4*)&wl[(ci + 3) * 64 + c0];
#pragma unroll
      for (int p = 0; p < 4; ++p) {
        float4 z4 = make_float4(0.f, 0.f, 0.f, 0.f);
        float4 xa = v[p] ? *(float4*)&xs[0][base[p] + ci] : z4;
        float4 xb = v[p] ? *(float4*)&xs[1][base[p] + ci] : z4;
        acc0[p] = f4fma(xa.x, w0, acc0[p]); acc0[p] = f4fma(xa.y, w1_, acc0[p]);
        acc0[p] = f4fma(xa.z, w2_, acc0[p]); acc0[p] = f4fma(xa.w, w3_, acc0[p]);
        acc1[p] = f4fma(xb.x, w0, acc1[p]); acc1[p] = f4fma(xb.y, w1_, acc1[p]);
        acc1[p] = f4fma(xb.z, w2_, acc1[p]); acc1[p] = f4fma(xb.w, w3_, acc1[p]);
      }
    }
  }
#pragma unroll
  for (int p = 0; p < 4; ++p)
    if (val[p]) {
      *(float4*)&h2[(n0 * 49 + sarr[p]) * 64 + c0] = f4relu(f4addrn(acc0[p], bias));
      *(float4*)&h2[((n0 + 1) * 49 + sarr[p]) * 64 + c0] = f4relu(f4addrn(acc1[p], bias));
    }
}

// ---- K_pw: 1x1 conv 64->64, bias-after (no act). NHWC ----------------------
__global__ __launch_bounds__(256) void k_pw(const float* __restrict__ xin,
                                            const float* __restrict__ w,     // [ci][co]
                                            const float* __restrict__ bias,
                                            float* __restrict__ yout) {
  __shared__ float tile[256 * 65];
  int t = threadIdx.x;
  long m0 = (long)blockIdx.x * 256;
  for (int j = t; j < 16384; j += 256) tile[(j >> 6) * 65 + (j & 63)] = xin[m0 * 64 + j];
  __syncthreads();
  float xr[64];
#pragma unroll
  for (int ci = 0; ci < 64; ++ci) xr[ci] = tile[t * 65 + ci];
  for (int g = 0; g < 4; ++g) {
    float4 z4 = make_float4(0.f, 0.f, 0.f, 0.f);
    float4 a0 = z4, a1 = z4, a2 = z4, a3 = z4;
#pragma unroll
    for (int ci = 0; ci < 64; ++ci) {
      float xv = xr[ci];
      const float* wr = &w[ci * 64 + g * 16];
      a0 = f4fma(xv, *(const float4*)&wr[0], a0);
      a1 = f4fma(xv, *(const float4*)&wr[4], a1);
      a2 = f4fma(xv, *(const float4*)&wr[8], a2);
      a3 = f4fma(xv, *(const float4*)&wr[12], a3);
    }
    a0 = f4addrn(a0, *(const float4*)&bias[g * 16 + 0]);
    a1 = f4addrn(a1, *(const float4*)&bias[g * 16 + 4]);
    a2 = f4addrn(a2, *(const float4*)&bias[g * 16 + 8]);
    a3 = f4addrn(a3, *(const float4*)&bias[g * 16 + 12]);
    float* dst = &tile[t * 65 + g * 16];
    dst[0] = a0.x; dst[1] = a0.y; dst[2] = a0.z; dst[3] = a0.w;
    dst[4] = a1.x; dst[5] = a1.y; dst[6] = a1.z; dst[7] = a1.w;
    dst[8] = a2.x; dst[9] = a2.y; dst[10] = a2.z; dst[11] = a2.w;
    dst[12] = a3.x; dst[13] = a3.y; dst[14] = a3.z; dst[15] = a3.w;
  }
  __syncthreads();
  for (int j = t; j < 16384; j += 256) yout[m0 * 64 + j] = tile[(j >> 6) * 65 + (j & 63)];
}

// ---- K4: VQ. z NHWC -> idx, z NCHW, z_q NCHW, zq NHWC, loss ----------------
__global__ __launch_bounds__(256) void k4_vq(const float* __restrict__ zin,
                                             const float* __restrict__ cb,
                                             const float* __restrict__ cn,
                                             float* __restrict__ zq_nhwc,
                                             float* __restrict__ outz,
                                             float* __restrict__ outzq,
                                             float* __restrict__ outidx,
                                             float* __restrict__ loss) {
  __shared__ float tile[256 * 65];
  __shared__ float red[4];
  int t = threadIdx.x;
  long m0 = (long)blockIdx.x * 256;
  for (int j = t; j < 16384; j += 256) tile[(j >> 6) * 65 + (j & 63)] = zin[m0 * 64 + j];
  __syncthreads();
  float zr[64];
#pragma unroll
  for (int ci = 0; ci < 64; ++ci) zr[ci] = tile[t * 65 + ci];
  unsigned m = (unsigned)(m0 + t);
  unsigned n = m / 49u, sp = m % 49u;
  float* zob = outz + (size_t)n * 3136 + sp;
#pragma unroll
  for (int ci = 0; ci < 64; ++ci) zob[ci * 49] = zr[ci];
  // ---- np-exact argmin: dist = fl( fl(SZ + SC_k) - 2*dot ), first-min-wins.
  float sz = np_sumsq64(zr);
  float minv = 3.4e38f; int mini = 0;
  for (int k = 0; k < 512; ++k) {
    float d = 0.f;  // sequential-K fma chain (BLAS sgemm accumulation order)
#pragma unroll
    for (int ci = 0; ci < 64; ci += 4) {
      float4 c4 = *(const float4*)&cb[k * 64 + ci];
      d = fmaf(zr[ci + 0], c4.x, d);
      d = fmaf(zr[ci + 1], c4.y, d);
      d = fmaf(zr[ci + 2], c4.z, d);
      d = fmaf(zr[ci + 3], c4.w, d);
    }
    float dist = __fsub_rn(__fadd_rn(sz, cn[k]), __fmul_rn(2.f, d));
    if (dist < minv) { minv = dist; mini = k; }
  }
  outidx[m] = (float)mini;
  float* qob = outzq + (size_t)n * 3136 + sp;
  float lsum = 0.f;
#pragma unroll
  for (int ci = 0; ci < 64; ci += 4) {
    float4 q4 = *(const float4*)&cb[mini * 64 + ci];
    float* dst = &tile[t * 65 + ci];
    dst[0] = q4.x; dst[1] = q4.y; dst[2] = q4.z; dst[3] = q4.w;
    qob[(ci + 0) * 49] = q4.x; qob[(ci + 1) * 49] = q4.y;
    qob[(ci + 2) * 49] = q4.z; qob[(ci + 3) * 49] = q4.w;
    float e0 = q4.x - zr[ci + 0], e1 = q4.y - zr[ci + 1];
    float e2 = q4.z - zr[ci + 2], e3 = q4.w - zr[ci + 3];
    lsum = fmaf(e0, e0, lsum); lsum = fmaf(e1, e1, lsum);
    lsum = fmaf(e2, e2, lsum); lsum = fmaf(e3, e3, lsum);
  }
#pragma unroll
  for (int off = 32; off > 0; off >>= 1) lsum += __shfl_down(lsum, off);
  int wid = t >> 6, lane = t & 63;
  if (lane == 0) red[wid] = lsum;
  __syncthreads();
  if (t == 0) atomicAdd(loss, red[0] + red[1] + red[2] + red[3]);
  for (int j = t; j < 16384; j += 256) zq_nhwc[m0 * 64 + j] = tile[(j >> 6) * 65 + (j & 63)];
}

// ---- K4b: finalize loss ----------------------------------------------------
__global__ __launch_bounds__(64) void k_lossfin(const float* __restrict__ loss,
                                                float* __restrict__ out) {
  if (threadIdx.x == 0) out[0] = loss[0] * (1.25f / 12845056.f);
}

// ---- K6: deconv1 4x4 s2 p2 (lhs_dilation), 64->32, ReLU. NHWC --------------
// Polyphase: output (oh=2*mh+ra, ow=2*mw+rb); tap (th,tw) uses kernel
// (kh=2*th+ra, kw=2*tw+rb), input (mh+th+ra-1, mw+tw+rb-1). G=2 images/block,
// register-prefetched weight slices, 16 stagings linearized over (ph,tap).
__global__ __launch_bounds__(256) void k6_deconv1(const float* __restrict__ d0,
                                                  const float* __restrict__ dw1,
                                                  const float* __restrict__ db1,
                                                  float* __restrict__ d1) {
  __shared__ float xsp[2][81 * 68];  // 9x9 zero-padded grid, 64ci padded to 68
  __shared__ float wl[2048];         // one (kh,kw) slice: [ci][32co]
  int nb = blockIdx.x, t = threadIdx.x;
  size_t n0 = (size_t)nb * 2;
  for (int j = t; j < 81 * 68; j += 256) { xsp[0][j] = 0.f; xsp[1][j] = 0.f; }
  __syncthreads();
  for (int j = t; j < 3136; j += 256) {
    int p = j >> 6, ci = j & 63;
    int off = ((p / 7 + 1) * 9 + (p % 7 + 1)) * 68 + ci;
    xsp[0][off] = d0[n0 * 3136 + j];
    xsp[1][off] = d0[(n0 + 1) * 3136 + j];
  }
  int g = t & 7, pg = t >> 3, c0 = g * 4;
  float4 bias = *(const float4*)&db1[c0];
  int s0 = pg, s1 = pg + 32;
  bool v1 = (s1 < 49);
  int mh0 = s0 / 7, mw0 = s0 % 7;
  int mh1 = v1 ? s1 / 7 : 0, mw1 = v1 ? s1 % 7 : 0;
  // prefetch st=0 slice (ph=0,tap=0 -> kh=0,kw=0)
  float4 wr0 = *(const float4*)&dw1[t * 8];
  float4 wr1 = *(const float4*)&dw1[t * 8 + 4];
  float4 a00, a01, a10, a11;  // [im][pos]
#pragma unroll 1
  for (int st = 0; st < 16; ++st) {
    int ph = st >> 2, tap = st & 3;
    int ra = ph >> 1, rb = ph & 1, th = tap >> 1, tw = tap & 1;
    __syncthreads();
    *(float4*)&wl[t * 8] = wr0;
    *(float4*)&wl[t * 8 + 4] = wr1;
    __syncthreads();
    if (st < 15) {
      int st2 = st + 1, ph2 = st2 >> 2, tap2 = st2 & 3;
      int kh2 = 2 * (tap2 >> 1) + (ph2 >> 1), kw2 = 2 * (tap2 & 1) + (ph2 & 1);
      const float* wp = &dw1[(kh2 * 4 + kw2) * 2048 + t * 8];
      wr0 = *(const float4*)wp; wr1 = *(const float4*)(wp + 4);
    }
    if (tap == 0) {
      a00 = make_float4(0.f, 0.f, 0.f, 0.f);
      a01 = a00; a10 = a00; a11 = a00;
    }
    int bb0 = ((mh0 + th + ra) * 9 + (mw0 + tw + rb)) * 68;
    int bb1 = ((mh1 + th + ra) * 9 + (mw1 + tw + rb)) * 68;
#pragma unroll
    for (int ci = 0; ci < 64; ci += 4) {
      float4 w0 = *(float4*)&wl[(ci + 0) * 32 + c0];
      float4 w1_ = *(float4*)&wl[(ci + 1) * 32 + c0];
      float4 w2_ = *(float4*)&wl[(ci + 2) * 32 + c0];
      float4 w3_ = *(float4*)&wl[(ci + 3) * 32 + c0];
      float4 xa0 = *(float4*)&xsp[0][bb0 + ci];
      float4 xa1 = *(float4*)&xsp[0][bb1 + ci];
      float4 xb0 = *(float4*)&xsp[1][bb0 + ci];
      float4 xb1 = *(float4*)&xsp[1][bb1 + ci];
      a00 = f4fma(xa0.x, w0, a00); a00 = f4fma(xa0.y, w1_, a00);
      a00 = f4fma(xa0.z, w2_, a00); a00 = f4fma(xa0.w, w3_, a00);
      a01 = f4fma(xa1.x, w0, a01); a01 = f4fma(xa1.y, w1_, a01);
      a01 = f4fma(xa1.z, w2_, a01); a01 = f4fma(xa1.w, w3_, a01);
      a10 = f4fma(xb0.x, w0, a10); a10 = f4fma(xb0.y, w1_, a10);
      a10 = f4fma(xb0.z, w2_, a10); a10 = f4fma(xb0.w, w3_, a10);
      a11 = f4fma(xb1.x, w0, a11); a11 = f4fma(xb1.y, w1_, a11);
      a11 = f4fma(xb1.z, w2_, a11); a11 = f4fma(xb1.w, w3_, a11);
    }
    if (tap == 3) {
      int oh0 = 2 * mh0 + ra, ow0 = 2 * mw0 + rb;
      *(float4*)&d1[(n0 * 196 + oh0 * 14 + ow0) * 32 + c0] =
          f4relu(f4addrn(a00, bias));
      *(float4*)&d1[((n0 + 1) * 196 + oh0 * 14 + ow0) * 32 + c0] =
          f4relu(f4addrn(a10, bias));
      if (v1) {
        int oh1 = 2 * mh1 + ra, ow1 = 2 * mw1 + rb;
        *(float4*)&d1[(n0 * 196 + oh1 * 14 + ow1) * 32 + c0] =
            f4relu(f4addrn(a01, bias));
        *(float4*)&d1[((n0 + 1) * 196 + oh1 * 14 + ow1) * 32 + c0] =
            f4relu(f4addrn(a11, bias));
      }
    }
  }
}

// ---- K7: deconv2 4x4 s2 p2, 32->1, sigmoid -> recon NCHW -------------------
__global__ __launch_bounds__(256) void k7_deconv2(const float* __restrict__ d1,
                                                  const float* __restrict__ dw2,
                                                  const float* __restrict__ db2,
                                                  float* __restrict__ recon) {
  __shared__ float xs[196 * 36];
  __shared__ float wl[512];
  int n = blockIdx.x, t = threadIdx.x;
  for (int j = t; j < 6272; j += 256) xs[(j >> 5) * 36 + (j & 31)] = d1[(size_t)n * 6272 + j];
  for (int j = t; j < 512; j += 256) wl[j] = dw2[j];
  __syncthreads();
  float bias = db2[0];
  for (int j = t; j < 392; j += 256) {
    int ra = j / 196, rem = j % 196;
    int mh = rem / 14, mw = rem % 14;
    float acc0 = bias, acc1 = bias;
    bool vm = (mw >= 1), vp = (mw + 1 < 14);
#pragma unroll
    for (int th = 0; th < 2; ++th) {
      int ih = mh + th - 1 + ra;
      if (ih < 0 || ih >= 14) continue;
      int kh = 2 * th + ra;
#pragma unroll
      for (int ci = 0; ci < 32; ci += 4) {
        float4 z4 = make_float4(0.f, 0.f, 0.f, 0.f);
        float4 xm = vm ? *(float4*)&xs[(ih * 14 + mw - 1) * 36 + ci] : z4;
        float4 x0 = *(float4*)&xs[(ih * 14 + mw) * 36 + ci];
        float4 xp = vp ? *(float4*)&xs[(ih * 14 + mw + 1) * 36 + ci] : z4;
        float4 wk0 = *(float4*)&wl[(kh * 4 + 0) * 32 + ci];
        float4 wk1 = *(float4*)&wl[(kh * 4 + 1) * 32 + ci];
        float4 wk2 = *(float4*)&wl[(kh * 4 + 2) * 32 + ci];
        float4 wk3 = *(float4*)&wl[(kh * 4 + 3) * 32 + ci];
        acc0 = fmaf(xm.x, wk0.x, acc0); acc0 = fmaf(xm.y, wk0.y, acc0);
        acc0 = fmaf(xm.z, wk0.z, acc0); acc0 = fmaf(xm.w, wk0.w, acc0);
        acc0 = fmaf(x0.x, wk2.x, acc0); acc0 = fmaf(x0.y, wk2.y, acc0);
        acc0 = fmaf(x0.z, wk2.z, acc0); acc0 = fmaf(x0.w, wk2.w, acc0);
        acc1 = fmaf(x0.x, wk1.x, acc1); acc1 = fmaf(x0.y, wk1.y, acc1);
        acc1 = fmaf(x0.z, wk1.z, acc1); acc1 = fmaf(x0.w, wk1.w, acc1);
        acc1 = fmaf(xp.x, wk3.x, acc1); acc1 = fmaf(xp.y, wk3.y, acc1);
        acc1 = fmaf(xp.z, wk3.z, acc1); acc1 = fmaf(xp.w, wk3.w, acc1);
      }
    }
    float r0 = 1.f / (1.f + __expf(-acc0));
    float r1 = 1.f / (1.f + __expf(-acc1));
    int oh = 2 * mh + ra;
    *(float2*)&recon[(size_t)n * 784 + oh * 28 + 2 * mw] = make_float2(r0, r1);
  }
}

extern "C" void kernel_launch(void* const* d_in, const int* in_sizes, int n_in,
                              void* d_out, int out_size, void* d_ws, size_t ws_size,
                              hipStream_t stream) {
  const float* x   = (const float*)d_in[0];
  const float* w1  = (const float*)d_in[1];
  const float* b1  = (const float*)d_in[2];
  const float* w2  = (const float*)d_in[3];
  const float* b2  = (const float*)d_in[4];
  const float* w3  = (const float*)d_in[5];
  const float* b3  = (const float*)d_in[6];
  const float* cb  = (const float*)d_in[7];
  const float* dw0 = (const float*)d_in[8];
  const float* db0 = (const float*)d_in[9];
  const float* dw1 = (const float*)d_in[10];
  const float* db1 = (const float*)d_in[11];
  const float* dw2 = (const float*)d_in[12];
  const float* db2 = (const float*)d_in[13];
  float* out = (float*)d_out;
  float* ws  = (float*)d_ws;

  float* h1   = ws;                 // 25,690,112 (reused as d1)
  float* h2   = ws + 25690112;      // 12,845,056 (reused as zq_nhwc)
  float* zb   = ws + 38535168;      // 12,845,056 z_nhwc (reused as d0)
  float* cn   = ws + 51380224;      // 512
  float* loss = ws + 51380736;      // 1

  float* recon   = out;
  float* zout    = out + 3211264;
  float* zqout   = out + 16056320;
  float* lossout = out + 28901376;
  float* idxout  = out + 28901377;

  k0_init<<<1, 256, 0, stream>>>(cb, cn, loss);
  k1_conv1<<<NB, 256, 0, stream>>>(x, w1, b1, h1);
  k2_conv2<<<NB / 2, 256, 0, stream>>>(h1, w2, b2, h2);
  k_pw<<<784, 256, 0, stream>>>(h2, w3, b3, zb);                 // z = h2 @ w3 + b3
  k4_vq<<<784, 256, 0, stream>>>(zb, cb, cn, h2, zout, zqout, idxout, loss);
  k_lossfin<<<1, 64, 0, stream>>>(loss, lossout);
  k_pw<<<784, 256, 0, stream>>>(h2, dw0, db0, zb);               // d0 = zq @ dw0 + db0
  k6_deconv1<<<NB / 2, 256, 0, stream>>>(zb, dw1, db1, h1);
  k7_deconv2<<<NB, 256, 0, stream>>>(h1, dw2, db2, recon);
}

// Round 5
// 1254.520 us; speedup vs baseline: 1.4394x; 1.4394x over previous
//
#include <hip/hip_runtime.h>

// ============================================================================
// VQ-VAE forward, MI355X fp32. Internal layout NHWC; outputs NCHW.
// B=4096. x(4096,1,28,28) -> h1(4096,14,14,32) -> h2(4096,7,7,64)
//   -> z -> VQ(512 codes, D=64) -> d0 -> d1(4096,14,14,32) -> recon.
// VQ argmin reproduces np fp32 semantics exactly:
//   dist = fl( fl(SZ + SC_k) - 2*dot(z,c_k) ), SZ/SC via numpy pairwise-8,
//   dot via sequential-K fma (BLAS order), first-min-wins tie break.
// R2: unrolled tap loop -> 256-VGPR cap -> scratch spill -> 12 GB HBM.
// R3: barrier-per-slice weight staging -> global latency on critical path.
// R4 lesson: k2/k6 are LDS-READ-THROUGHPUT bound (96 ds_read_b128 vs 256
//   f4fma per kk). Fix: weights via wave-uniform s_load (readfirstlane) into
//   SGPRs -> zero LDS traffic for weights; x in a polyphase-swizzled padded
//   LDS grid (unconditional b128, balanced banks); 2pos x 16co register tile
//   -> 16:1 FMA:ds_read; K-loop has NO barriers.
// Workspace (floats): h1/d1 @0 (25,690,112) | h2/zq @25,690,112 (12,845,056)
//   | z/d0 @38,535,168 (12,845,056) | cn @51,380,224 (512) | loss @51,380,736
// Out (floats): recon@0, z@3,211,264, z_q@16,056,320, loss@28,901,376,
//   idx@28,901,377 (200,704)
// ============================================================================

#define NB 4096

__device__ __forceinline__ float4 f4fma(float s, float4 w, float4 a) {
  a.x = fmaf(s, w.x, a.x); a.y = fmaf(s, w.y, a.y);
  a.z = fmaf(s, w.z, a.z); a.w = fmaf(s, w.w, a.w);
  return a;
}
__device__ __forceinline__ float4 f4relu(float4 a) {
  a.x = fmaxf(a.x, 0.f); a.y = fmaxf(a.y, 0.f);
  a.z = fmaxf(a.z, 0.f); a.w = fmaxf(a.w, 0.f);
  return a;
}
__device__ __forceinline__ float4 f4addrn(float4 a, float4 b) {
  a.x = __fadd_rn(a.x, b.x); a.y = __fadd_rn(a.y, b.y);
  a.z = __fadd_rn(a.z, b.z); a.w = __fadd_rn(a.w, b.w);
  return a;
}

// numpy pairwise-8 sum of squares over 64 contiguous values
__device__ __forceinline__ float np_sumsq64(const float* v) {
  float r[8];
#pragma unroll
  for (int j = 0; j < 8; ++j) r[j] = __fmul_rn(v[j], v[j]);
#pragma unroll
  for (int i = 8; i < 64; i += 8)
#pragma unroll
    for (int j = 0; j < 8; ++j) r[j] = __fadd_rn(r[j], __fmul_rn(v[i + j], v[i + j]));
  return __fadd_rn(__fadd_rn(__fadd_rn(r[0], r[1]), __fadd_rn(r[2], r[3])),
                   __fadd_rn(__fadd_rn(r[4], r[5]), __fadd_rn(r[6], r[7])));
}

// ---- K0: codebook norms (numpy-order) + zero loss accumulator --------------
__global__ __launch_bounds__(256) void k0_init(const float* __restrict__ cb,
                                               float* __restrict__ cn,
                                               float* __restrict__ loss) {
  int t = threadIdx.x;
  if (t == 0) *loss = 0.f;
  for (int k = t; k < 512; k += 256) cn[k] = np_sumsq64(&cb[k * 64]);
}

// ---- K1: conv1 4x4 s2 p1, 1->32, bias-after, ReLU. out h1 NHWC -------------
__global__ __launch_bounds__(256) void k1_conv1(const float* __restrict__ x,
                                                const float* __restrict__ w1,
                                                const float* __restrict__ b1,
                                                float* __restrict__ h1) {
  __shared__ float xs[784];
  __shared__ float wl[512];
  __shared__ float bs[32];
  int n = blockIdx.x, t = threadIdx.x;
  for (int j = t; j < 784; j += 256) xs[j] = x[n * 784 + j];
  for (int j = t; j < 512; j += 256) wl[j] = w1[j];
  if (t < 32) bs[t] = b1[t];
  __syncthreads();
  int c = t & 31, pg = t >> 5;
  for (int s = pg; s < 196; s += 8) {
    int oh = s / 14, ow = s % 14;
    float acc = 0.f;
#pragma unroll
    for (int kh = 0; kh < 4; ++kh) {
      int ih = 2 * oh - 1 + kh;
      if (ih < 0 || ih >= 28) continue;
#pragma unroll
      for (int kw = 0; kw < 4; ++kw) {
        int iw = 2 * ow - 1 + kw;
        if (iw < 0 || iw >= 28) continue;
        acc = fmaf(xs[ih * 28 + iw], wl[(kh * 4 + kw) * 32 + c], acc);
      }
    }
    acc = __fadd_rn(acc, bs[c]);
    h1[(n * 196 + s) * 32 + c] = fmaxf(acc, 0.f);
  }
}

// ---- K2: conv2 4x4 s2 p1, 32->64, bias-after, ReLU. NHWC -------------------
// 2 img/block. x in padded polyphase LDS grid [c4:8][row:16][par:2][col8:8]
// (f4 chunks, img stride 2049). Weights via wave-uniform s_load (16 co/wave).
// Thread: 2 positions x 16 co. K-loop barrier-free.
__global__ __launch_bounds__(256) void k2_conv2(const float* __restrict__ h1,
                                                const float* __restrict__ w2,
                                                const float* __restrict__ b2,
                                                float* __restrict__ h2) {
  __shared__ float4 xs4[2 * 2049];
  int nb = blockIdx.x, t = threadIdx.x;
  size_t n0 = (size_t)nb * 2;
  for (int j = t; j < 4098; j += 256) xs4[j] = make_float4(0.f, 0.f, 0.f, 0.f);
  __syncthreads();
  for (int j = t; j < 1568; j += 256) {
    int p = j >> 3, c4 = j & 7;
    int ihp = p / 14 + 1, iwp = p % 14 + 1;
    int chunk = (c4 * 16 + ihp) * 16 + (iwp & 1) * 8 + (iwp >> 1);
    xs4[chunk] = *(const float4*)(h1 + n0 * 6272 + p * 32 + c4 * 4);
    xs4[2049 + chunk] = *(const float4*)(h1 + (n0 + 1) * 6272 + p * 32 + c4 * 4);
  }
  __syncthreads();
  int l = t & 63;
  int co0 = __builtin_amdgcn_readfirstlane((t >> 6) * 16);
  int img = l >> 5, pt = l & 31;
  int oh0 = pt >> 3, ow = pt & 7;
  int imgoff = img * 2049;
  bool v0 = (ow < 7);
  bool v1 = (ow < 7) && (oh0 + 4 < 7);
  float4 A0[4], A1[4];
#pragma unroll
  for (int g = 0; g < 4; ++g) { A0[g] = make_float4(0.f, 0.f, 0.f, 0.f); A1[g] = A0[g]; }
#pragma unroll 1
  for (int kk = 0; kk < 16; ++kk) {
    int kh = kk >> 2, kw = kk & 3;
    int cc = 2 * ow + kw; if (cc > 15) cc = 15;
    int off = (cc & 1) * 8 + (cc >> 1);
    int rc0 = 2 * oh0 + kh;
    int rc1 = rc0 + 8; if (rc1 > 15) rc1 = 15;
    int b0 = imgoff + rc0 * 16 + off;
    int b1 = imgoff + rc1 * 16 + off;
    int wb = __builtin_amdgcn_readfirstlane(kk * 2048 + co0);
#pragma unroll 2
    for (int c4 = 0; c4 < 8; ++c4) {
      float4 x0 = xs4[b0 + c4 * 256];
      float4 x1 = xs4[b1 + c4 * 256];
      float xa0[4] = {x0.x, x0.y, x0.z, x0.w};
      float xa1[4] = {x1.x, x1.y, x1.z, x1.w};
      const float* wk = w2 + wb + c4 * 256;
#pragma unroll
      for (int j = 0; j < 4; ++j) {
#pragma unroll
        for (int g = 0; g < 4; ++g) {
          float4 wv4;
          wv4.x = wk[j * 64 + g * 4 + 0]; wv4.y = wk[j * 64 + g * 4 + 1];
          wv4.z = wk[j * 64 + g * 4 + 2]; wv4.w = wk[j * 64 + g * 4 + 3];
          A0[g] = f4fma(xa0[j], wv4, A0[g]);
          A1[g] = f4fma(xa1[j], wv4, A1[g]);
        }
      }
    }
  }
  float4 bias[4];
#pragma unroll
  for (int g = 0; g < 4; ++g) bias[g] = *(const float4*)&b2[co0 + g * 4];
  if (v0) {
    size_t ob = ((n0 + img) * 49 + oh0 * 7 + ow) * 64 + co0;
#pragma unroll
    for (int g = 0; g < 4; ++g)
      *(float4*)&h2[ob + g * 4] = f4relu(f4addrn(A0[g], bias[g]));
  }
  if (v1) {
    size_t ob = ((n0 + img) * 49 + (oh0 + 4) * 7 + ow) * 64 + co0;
#pragma unroll
    for (int g = 0; g < 4; ++g)
      *(float4*)&h2[ob + g * 4] = f4relu(f4addrn(A1[g], bias[g]));
  }
}

// ---- K_pw: 1x1 conv 64->64, bias-after (no act). NHWC ----------------------
__global__ __launch_bounds__(256) void k_pw(const float* __restrict__ xin,
                                            const float* __restrict__ w,     // [ci][co]
                                            const float* __restrict__ bias,
                                            float* __restrict__ yout) {
  __shared__ float tile[256 * 65];
  int t = threadIdx.x;
  long m0 = (long)blockIdx.x * 256;
  for (int j = t; j < 16384; j += 256) tile[(j >> 6) * 65 + (j & 63)] = xin[m0 * 64 + j];
  __syncthreads();
  float xr[64];
#pragma unroll
  for (int ci = 0; ci < 64; ++ci) xr[ci] = tile[t * 65 + ci];
  for (int g = 0; g < 4; ++g) {
    float4 z4 = make_float4(0.f, 0.f, 0.f, 0.f);
    float4 a0 = z4, a1 = z4, a2 = z4, a3 = z4;
#pragma unroll
    for (int ci = 0; ci < 64; ++ci) {
      float xv = xr[ci];
      const float* wr = &w[ci * 64 + g * 16];
      a0 = f4fma(xv, *(const float4*)&wr[0], a0);
      a1 = f4fma(xv, *(const float4*)&wr[4], a1);
      a2 = f4fma(xv, *(const float4*)&wr[8], a2);
      a3 = f4fma(xv, *(const float4*)&wr[12], a3);
    }
    a0 = f4addrn(a0, *(const float4*)&bias[g * 16 + 0]);
    a1 = f4addrn(a1, *(const float4*)&bias[g * 16 + 4]);
    a2 = f4addrn(a2, *(const float4*)&bias[g * 16 + 8]);
    a3 = f4addrn(a3, *(const float4*)&bias[g * 16 + 12]);
    float* dst = &tile[t * 65 + g * 16];
    dst[0] = a0.x; dst[1] = a0.y; dst[2] = a0.z; dst[3] = a0.w;
    dst[4] = a1.x; dst[5] = a1.y; dst[6] = a1.z; dst[7] = a1.w;
    dst[8] = a2.x; dst[9] = a2.y; dst[10] = a2.z; dst[11] = a2.w;
    dst[12] = a3.x; dst[13] = a3.y; dst[14] = a3.z; dst[15] = a3.w;
  }
  __syncthreads();
  for (int j = t; j < 16384; j += 256) yout[m0 * 64 + j] = tile[(j >> 6) * 65 + (j & 63)];
}

// ---- K4: VQ. z NHWC -> idx, z NCHW, z_q NCHW, zq NHWC, loss ----------------
__global__ __launch_bounds__(256) void k4_vq(const float* __restrict__ zin,
                                             const float* __restrict__ cb,
                                             const float* __restrict__ cn,
                                             float* __restrict__ zq_nhwc,
                                             float* __restrict__ outz,
                                             float* __restrict__ outzq,
                                             float* __restrict__ outidx,
                                             float* __restrict__ loss) {
  __shared__ float tile[256 * 65];
  __shared__ float red[4];
  int t = threadIdx.x;
  long m0 = (long)blockIdx.x * 256;
  for (int j = t; j < 16384; j += 256) tile[(j >> 6) * 65 + (j & 63)] = zin[m0 * 64 + j];
  __syncthreads();
  float zr[64];
#pragma unroll
  for (int ci = 0; ci < 64; ++ci) zr[ci] = tile[t * 65 + ci];
  unsigned m = (unsigned)(m0 + t);
  unsigned n = m / 49u, sp = m % 49u;
  float* zob = outz + (size_t)n * 3136 + sp;
#pragma unroll
  for (int ci = 0; ci < 64; ++ci) zob[ci * 49] = zr[ci];
  // ---- np-exact argmin: dist = fl( fl(SZ + SC_k) - 2*dot ), first-min-wins.
  float sz = np_sumsq64(zr);
  float minv = 3.4e38f; int mini = 0;
  for (int k = 0; k < 512; ++k) {
    float d = 0.f;  // sequential-K fma chain (BLAS sgemm accumulation order)
#pragma unroll
    for (int ci = 0; ci < 64; ci += 4) {
      float4 c4 = *(const float4*)&cb[k * 64 + ci];
      d = fmaf(zr[ci + 0], c4.x, d);
      d = fmaf(zr[ci + 1], c4.y, d);
      d = fmaf(zr[ci + 2], c4.z, d);
      d = fmaf(zr[ci + 3], c4.w, d);
    }
    float dist = __fsub_rn(__fadd_rn(sz, cn[k]), __fmul_rn(2.f, d));
    if (dist < minv) { minv = dist; mini = k; }
  }
  outidx[m] = (float)mini;
  float* qob = outzq + (size_t)n * 3136 + sp;
  float lsum = 0.f;
#pragma unroll
  for (int ci = 0; ci < 64; ci += 4) {
    float4 q4 = *(const float4*)&cb[mini * 64 + ci];
    float* dst = &tile[t * 65 + ci];
    dst[0] = q4.x; dst[1] = q4.y; dst[2] = q4.z; dst[3] = q4.w;
    qob[(ci + 0) * 49] = q4.x; qob[(ci + 1) * 49] = q4.y;
    qob[(ci + 2) * 49] = q4.z; qob[(ci + 3) * 49] = q4.w;
    float e0 = q4.x - zr[ci + 0], e1 = q4.y - zr[ci + 1];
    float e2 = q4.z - zr[ci + 2], e3 = q4.w - zr[ci + 3];
    lsum = fmaf(e0, e0, lsum); lsum = fmaf(e1, e1, lsum);
    lsum = fmaf(e2, e2, lsum); lsum = fmaf(e3, e3, lsum);
  }
#pragma unroll
  for (int off = 32; off > 0; off >>= 1) lsum += __shfl_down(lsum, off);
  int wid = t >> 6, lane = t & 63;
  if (lane == 0) red[wid] = lsum;
  __syncthreads();
  if (t == 0) atomicAdd(loss, red[0] + red[1] + red[2] + red[3]);
  for (int j = t; j < 16384; j += 256) zq_nhwc[m0 * 64 + j] = tile[(j >> 6) * 65 + (j & 63)];
}

// ---- K4b: finalize loss ----------------------------------------------------
__global__ __launch_bounds__(64) void k_lossfin(const float* __restrict__ loss,
                                                float* __restrict__ out) {
  if (threadIdx.x == 0) out[0] = loss[0] * (1.25f / 12845056.f);
}

// ---- K6: deconv1 4x4 s2 p2 (lhs_dilation), 64->32, ReLU. NHWC --------------
// Wave = phase (ra=oh&1, rb=ow&1); x staged ONCE in padded grid
// [c4:16][row:9][col:9] f4 chunks (img stride 1297). Weights via s_load.
// Thread: 2 positions x 32 co. K-loop barrier-free, no per-phase restage.
__global__ __launch_bounds__(256) void k6_deconv1(const float* __restrict__ d0,
                                                  const float* __restrict__ dw1,
                                                  const float* __restrict__ db1,
                                                  float* __restrict__ d1) {
  __shared__ float4 xs4[2 * 1297];
  int nb = blockIdx.x, t = threadIdx.x;
  size_t n0 = (size_t)nb * 2;
  for (int j = t; j < 2594; j += 256) xs4[j] = make_float4(0.f, 0.f, 0.f, 0.f);
  __syncthreads();
  for (int j = t; j < 784; j += 256) {
    int p = j >> 4, c4 = j & 15;
    int chunk = c4 * 81 + (p / 7 + 1) * 9 + (p % 7 + 1);
    xs4[chunk] = *(const float4*)(d0 + n0 * 3136 + p * 64 + c4 * 4);
    xs4[1297 + chunk] = *(const float4*)(d0 + (n0 + 1) * 3136 + p * 64 + c4 * 4);
  }
  __syncthreads();
  int l = t & 63;
  int ph = __builtin_amdgcn_readfirstlane(t >> 6);
  int ra = ph >> 1, rb = ph & 1;
  int img = l >> 5, pt = l & 31;
  bool v1 = (pt + 32 < 49);
  int p1 = v1 ? pt + 32 : 48;
  int mh0 = pt / 7, mw0 = pt % 7;
  int mh1 = p1 / 7, mw1 = p1 % 7;
  int imgoff = img * 1297;
  float4 A0[8], A1[8];
#pragma unroll
  for (int g = 0; g < 8; ++g) { A0[g] = make_float4(0.f, 0.f, 0.f, 0.f); A1[g] = A0[g]; }
#pragma unroll 1
  for (int tap = 0; tap < 4; ++tap) {
    int th = tap >> 1, tw = tap & 1;
    int kh = 2 * th + ra, kw = 2 * tw + rb;
    int b0 = imgoff + (mh0 + th + ra) * 9 + (mw0 + tw + rb);
    int b1 = imgoff + (mh1 + th + ra) * 9 + (mw1 + tw + rb);
    int wb = __builtin_amdgcn_readfirstlane((kh * 4 + kw) * 2048);
#pragma unroll 1
    for (int c4 = 0; c4 < 16; ++c4) {
      float4 x0 = xs4[b0 + c4 * 81];
      float4 x1 = xs4[b1 + c4 * 81];
      float xa0[4] = {x0.x, x0.y, x0.z, x0.w};
      float xa1[4] = {x1.x, x1.y, x1.z, x1.w};
      const float* wk = dw1 + wb + c4 * 128;
#pragma unroll
      for (int j = 0; j < 4; ++j) {
#pragma unroll
        for (int g = 0; g < 8; ++g) {
          float4 wv4;
          wv4.x = wk[j * 32 + g * 4 + 0]; wv4.y = wk[j * 32 + g * 4 + 1];
          wv4.z = wk[j * 32 + g * 4 + 2]; wv4.w = wk[j * 32 + g * 4 + 3];
          A0[g] = f4fma(xa0[j], wv4, A0[g]);
          A1[g] = f4fma(xa1[j], wv4, A1[g]);
        }
      }
    }
  }
  int oh0 = 2 * mh0 + ra, ow0 = 2 * mw0 + rb;
  size_t ob0 = ((n0 + img) * 196 + (size_t)(oh0 * 14 + ow0)) * 32;
#pragma unroll
  for (int g = 0; g < 8; ++g) {
    float4 bg = *(const float4*)&db1[g * 4];
    *(float4*)&d1[ob0 + g * 4] = f4relu(f4addrn(A0[g], bg));
  }
  if (v1) {
    int oh1 = 2 * mh1 + ra, ow1 = 2 * mw1 + rb;
    size_t ob1 = ((n0 + img) * 196 + (size_t)(oh1 * 14 + ow1)) * 32;
#pragma unroll
    for (int g = 0; g < 8; ++g) {
      float4 bg = *(const float4*)&db1[g * 4];
      *(float4*)&d1[ob1 + g * 4] = f4relu(f4addrn(A1[g], bg));
    }
  }
}

// ---- K7: deconv2 4x4 s2 p2, 32->1, sigmoid -> recon NCHW -------------------
__global__ __launch_bounds__(256) void k7_deconv2(const float* __restrict__ d1,
                                                  const float* __restrict__ dw2,
                                                  const float* __restrict__ db2,
                                                  float* __restrict__ recon) {
  __shared__ float xs[196 * 36];
  __shared__ float wl[512];
  int n = blockIdx.x, t = threadIdx.x;
  for (int j = t; j < 6272; j += 256) xs[(j >> 5) * 36 + (j & 31)] = d1[(size_t)n * 6272 + j];
  for (int j = t; j < 512; j += 256) wl[j] = dw2[j];
  __syncthreads();
  float bias = db2[0];
  for (int j = t; j < 392; j += 256) {
    int ra = j / 196, rem = j % 196;
    int mh = rem / 14, mw = rem % 14;
    float acc0 = bias, acc1 = bias;
    bool vm = (mw >= 1), vp = (mw + 1 < 14);
#pragma unroll
    for (int th = 0; th < 2; ++th) {
      int ih = mh + th - 1 + ra;
      if (ih < 0 || ih >= 14) continue;
      int kh = 2 * th + ra;
#pragma unroll
      for (int ci = 0; ci < 32; ci += 4) {
        float4 z4 = make_float4(0.f, 0.f, 0.f, 0.f);
        float4 xm = vm ? *(float4*)&xs[(ih * 14 + mw - 1) * 36 + ci] : z4;
        float4 x0 = *(float4*)&xs[(ih * 14 + mw) * 36 + ci];
        float4 xp = vp ? *(float4*)&xs[(ih * 14 + mw + 1) * 36 + ci] : z4;
        float4 wk0 = *(float4*)&wl[(kh * 4 + 0) * 32 + ci];
        float4 wk1 = *(float4*)&wl[(kh * 4 + 1) * 32 + ci];
        float4 wk2 = *(float4*)&wl[(kh * 4 + 2) * 32 + ci];
        float4 wk3 = *(float4*)&wl[(kh * 4 + 3) * 32 + ci];
        acc0 = fmaf(xm.x, wk0.x, acc0); acc0 = fmaf(xm.y, wk0.y, acc0);
        acc0 = fmaf(xm.z, wk0.z, acc0); acc0 = fmaf(xm.w, wk0.w, acc0);
        acc0 = fmaf(x0.x, wk2.x, acc0); acc0 = fmaf(x0.y, wk2.y, acc0);
        acc0 = fmaf(x0.z, wk2.z, acc0); acc0 = fmaf(x0.w, wk2.w, acc0);
        acc1 = fmaf(x0.x, wk1.x, acc1); acc1 = fmaf(x0.y, wk1.y, acc1);
        acc1 = fmaf(x0.z, wk1.z, acc1); acc1 = fmaf(x0.w, wk1.w, acc1);
        acc1 = fmaf(xp.x, wk3.x, acc1); acc1 = fmaf(xp.y, wk3.y, acc1);
        acc1 = fmaf(xp.z, wk3.z, acc1); acc1 = fmaf(xp.w, wk3.w, acc1);
      }
    }
    float r0 = 1.f / (1.f + __expf(-acc0));
    float r1 = 1.f / (1.f + __expf(-acc1));
    int oh = 2 * mh + ra;
    *(float2*)&recon[(size_t)n * 784 + oh * 28 + 2 * mw] = make_float2(r0, r1);
  }
}

extern "C" void kernel_launch(void* const* d_in, const int* in_sizes, int n_in,
                              void* d_out, int out_size, void* d_ws, size_t ws_size,
                              hipStream_t stream) {
  const float* x   = (const float*)d_in[0];
  const float* w1  = (const float*)d_in[1];
  const float* b1  = (const float*)d_in[2];
  const float* w2  = (const float*)d_in[3];
  const float* b2  = (const float*)d_in[4];
  const float* w3  = (const float*)d_in[5];
  const float* b3  = (const float*)d_in[6];
  const float* cb  = (const float*)d_in[7];
  const float* dw0 = (const float*)d_in[8];
  const float* db0 = (const float*)d_in[9];
  const float* dw1 = (const float*)d_in[10];
  const float* db1 = (const float*)d_in[11];
  const float* dw2 = (const float*)d_in[12];
  const float* db2 = (const float*)d_in[13];
  float* out = (float*)d_out;
  float* ws  = (float*)d_ws;

  float* h1   = ws;                 // 25,690,112 (reused as d1)
  float* h2   = ws + 25690112;      // 12,845,056 (reused as zq_nhwc)
  float* zb   = ws + 38535168;      // 12,845,056 z_nhwc (reused as d0)
  float* cn   = ws + 51380224;      // 512
  float* loss = ws + 51380736;      // 1

  float* recon   = out;
  float* zout    = out + 3211264;
  float* zqout   = out + 16056320;
  float* lossout = out + 28901376;
  float* idxout  = out + 28901377;

  k0_init<<<1, 256, 0, stream>>>(cb, cn, loss);
  k1_conv1<<<NB, 256, 0, stream>>>(x, w1, b1, h1);
  k2_conv2<<<NB / 2, 256, 0, stream>>>(h1, w2, b2, h2);
  k_pw<<<784, 256, 0, stream>>>(h2, w3, b3, zb);                 // z = h2 @ w3 + b3
  k4_vq<<<784, 256, 0, stream>>>(zb, cb, cn, h2, zout, zqout, idxout, loss);
  k_lossfin<<<1, 64, 0, stream>>>(loss, lossout);
  k_pw<<<784, 256, 0, stream>>>(h2, dw0, db0, zb);               // d0 = zq @ dw0 + db0
  k6_deconv1<<<NB / 2, 256, 0, stream>>>(zb, dw1, db1, h1);
  k7_deconv2<<<NB, 256, 0, stream>>>(h1, dw2, db2, recon);
}